// Round 5
// baseline (636.032 us; speedup 1.0000x reference)
//
#include <hip/hip_runtime.h>

// TeacherEmbeddingTransform: block-diagonal GEMM, fp32.
//   x: (16384, 2304), weight: (25600,1) flat, bias: (576,), out: (16384, 576)
//   Blocks: 16x [16->4], 32x [32->8], 16x [64->16]
// 36 chunks of 64 in-cols -> 16 out-cols each. HBM floor ~30 us; harness
// resets add ~181 us of fill time inside dur_us (2x 90us fills in profile).
//
// v4: register-blocked rows + k-staging.
//   wg = 256 thr = 4 waves covers 256 rows x 16 cols (4 units).
//   Lane owns 4 rows (lane+64j) x 4 cols (wave's quad) = 16 accumulators,
//   so each uniform weight b128 feeds 4 rows and each x b128 feeds 16 FMAs:
//   ds instr/unit drops 336 (v2) -> 144.
//   k processed in 4 stages of 16: x LDS buf = 256 rows x 16 k (stride 20,
//   16-B aligned) = 20 KB; +4 KB densified weights = 24 KB -> 6 wg/CU.
//   Stage s+1 prefetched into regs (4 float4/thr) while stage s computes;
//   stage slice = 64 B = exactly one cache line per x row.

#define BATCH   16384
#define IN_DIM  2304
#define OUT_DIM 576
#define CHUNKS  36
#define XS_LDW  20    // 16 + 4 pad floats; 80 B row stride (16-B aligned)

__global__ __launch_bounds__(256, 4) void fused_block_mm(
    const float* __restrict__ x, const float* __restrict__ w,
    const float* __restrict__ bias, float* __restrict__ out)
{
    __shared__ float xs[256 * XS_LDW];   // 20480 B, one 16-k stage
    __shared__ float wd[64 * 16];        // 4096 B, densified, k-major

    const int tid  = threadIdx.x;
    const int bx   = blockIdx.x;
    const int cj   = bx % CHUNKS;        // chunk id (uniform)
    const int rt   = bx / CHUNKS;        // 256-row tile id, 0..63
    const int row0 = rt * 256;

    // ---- prefetch stage 0: thread t -> rows (t>>2)+64i, k-quad t&3 ----
    const float* __restrict__ xsrc = x + (size_t)row0 * IN_DIM + cj * 64;
    const int lr = tid >> 2;             // 0..63
    const int lk = (tid & 3) << 2;       // 0,4,8,12
    float4 pf[4];
    #pragma unroll
    for (int i = 0; i < 4; ++i)
        pf[i] = *reinterpret_cast<const float4*>(
            xsrc + (size_t)(lr + 64 * i) * IN_DIM + lk);

    // ---- densify this chunk's weights into wd[64][16] (verified v2) ----
    if (cj < 4) {                        // group 1: 4 blocks of 16->4
        const int wbase = cj * 256;
        #pragma unroll
        for (int i = 0; i < 4; ++i) {
            const int e = tid + i * 256, k = e >> 4, c = e & 15, b = k >> 4;
            wd[e] = ((c >> 2) == b)
                  ? w[wbase + b * 64 + ((k & 15) << 2) + (c & 3)] : 0.0f;
        }
    } else if (cj < 20) {                // group 2: 2 blocks of 32->8
        const int wbase = 1024 + (cj - 4) * 512;
        #pragma unroll
        for (int i = 0; i < 4; ++i) {
            const int e = tid + i * 256, k = e >> 4, c = e & 15, b = k >> 5;
            wd[e] = ((c >> 3) == b)
                  ? w[wbase + b * 256 + ((k & 31) << 3) + (c & 7)] : 0.0f;
        }
    } else {                             // group 3: dense 64->16 block
        const int wbase = 9216 + (cj - 20) * 1024;
        #pragma unroll
        for (int i = 0; i < 4; ++i) {
            const int e = tid + i * 256;
            wd[e] = w[wbase + e];
        }
    }
    __syncthreads();                     // wd visible; xs not yet touched

    const int wv   = __builtin_amdgcn_readfirstlane(tid >> 6);
    const int lane = tid & 63;
    const int ocol = cj * 16 + (wv << 2);

    const float4 bv = *reinterpret_cast<const float4*>(bias + ocol);
    float4 acc[4] = {bv, bv, bv, bv};    // rows lane+64j, cols ocol..+3

    #pragma unroll
    for (int s = 0; s < 4; ++s) {
        // regs -> LDS (stage s)
        #pragma unroll
        for (int i = 0; i < 4; ++i)
            *reinterpret_cast<float4*>(&xs[(lr + 64 * i) * XS_LDW + lk]) = pf[i];
        __syncthreads();                 // stage s visible

        // prefetch stage s+1 (overlaps compute below)
        if (s < 3) {
            #pragma unroll
            for (int i = 0; i < 4; ++i)
                pf[i] = *reinterpret_cast<const float4*>(
                    xsrc + (size_t)(lr + 64 * i) * IN_DIM + (s + 1) * 16 + lk);
        }

        // compute stage s: 4 k-quads x 4 rows x 4 cols
        #pragma unroll
        for (int k4 = 0; k4 < 4; ++k4) {
            const int kb = (s << 4) + (k4 << 2);          // absolute k
            const float4 w0 = *reinterpret_cast<const float4*>(&wd[(kb+0)*16 + (wv<<2)]);
            const float4 w1 = *reinterpret_cast<const float4*>(&wd[(kb+1)*16 + (wv<<2)]);
            const float4 w2 = *reinterpret_cast<const float4*>(&wd[(kb+2)*16 + (wv<<2)]);
            const float4 w3 = *reinterpret_cast<const float4*>(&wd[(kb+3)*16 + (wv<<2)]);
            #pragma unroll
            for (int j = 0; j < 4; ++j) {
                const float4 xv = *reinterpret_cast<const float4*>(
                    &xs[(lane + 64 * j) * XS_LDW + (k4 << 2)]);
                acc[j].x += xv.x*w0.x + xv.y*w1.x + xv.z*w2.x + xv.w*w3.x;
                acc[j].y += xv.x*w0.y + xv.y*w1.y + xv.z*w2.y + xv.w*w3.y;
                acc[j].z += xv.x*w0.z + xv.y*w1.z + xv.z*w2.z + xv.w*w3.z;
                acc[j].w += xv.x*w0.w + xv.y*w1.w + xv.z*w2.w + xv.w*w3.w;
            }
        }
        if (s < 3) __syncthreads();      // all reads of stage s done
    }

    // ---- store: 4 rows x 16 B per lane; the 4 waves of the wg fill each
    // 64-B out line (cj*64 byte-aligned), merged in L2 ----
    #pragma unroll
    for (int j = 0; j < 4; ++j)
        *reinterpret_cast<float4*>(
            out + (size_t)(row0 + lane + 64 * j) * OUT_DIM + ocol) = acc[j];
}

extern "C" void kernel_launch(void* const* d_in, const int* in_sizes, int n_in,
                              void* d_out, int out_size, void* d_ws, size_t ws_size,
                              hipStream_t stream) {
    const float* x    = (const float*)d_in[0];
    const float* w    = (const float*)d_in[1];
    const float* bias = (const float*)d_in[2];
    float* out        = (float*)d_out;

    // 36 chunks x (16384/256 = 64) row tiles
    fused_block_mm<<<dim3(CHUNKS * 64), 256, 0, stream>>>(x, w, bias, out);
}

// Round 6
// 235.424 us; speedup vs baseline: 2.7017x; 2.7017x over previous
//
#include <hip/hip_runtime.h>

// TeacherEmbeddingTransform: block-diagonal GEMM, fp32.
//   x: (16384, 2304), weight: (25600,1) flat, bias: (576,), out: (16384, 576)
//   36 chunks of 64 in-cols -> 16 out-cols each.
// HBM floor ~30 us (151 MB rd + 38 MB wr); harness fills add ~181 us to dur_us.
//
// History: v2 (wave=4 cols, 4 waves/tile) = ~48 us, LDS-issue-bound
//   (320 b128-instr/unit * 12 cyc = 57 us model). v4's k-staged pipeline
//   exploded HBM traffic (690 MB rd / 1019 MB wr measured) -> 497 us. REVERTED.
//
// v5: v2's exact global patterns + 4x4 register blocking, ONE WAVE PER UNIT.
//   unit = 64 rows x 64 k -> 16 cols. lane = (rq, cq): rows rq*4..+3,
//   cols cq*4..+3, 16 accumulators. Per k4: 4 x-b128 (16 addrs, 2-way banks
//   = free; 4-lane broadcast) + 4 w-b128 (16-way broadcast, conflict-free)
//   -> 64 FMAs. 128 b128/lane/unit vs v2's 320 wave-instr -> LDS issue
//   ~26 us/CU. Staging: wave-private tile, contiguous 256 B/row float4
//   reads (v2-proven), NO barrier (same-wave dep). Stores: each instr
//   writes 16 complete aligned 64-B runs. wg=128 (2 waves, shared 4 KB
//   densified wd, 38.9 KB LDS) -> 4 wg/CU = 8 waves/CU.

#define BATCH   16384
#define IN_DIM  2304
#define OUT_DIM 576
#define CHUNKS  36
#define XS_LDW  68   // 64 + 4 pad floats; 2-way max bank aliasing on reads

__global__ __launch_bounds__(128, 2) void fused_block_mm(
    const float* __restrict__ x, const float* __restrict__ w,
    const float* __restrict__ bias, float* __restrict__ out)
{
    __shared__ float wd[64 * 16];            // densified weights, k-major
    __shared__ float xs[2][64 * XS_LDW];     // per-wave private x tiles

    const int tid = threadIdx.x;
    const int bx  = blockIdx.x;
    const int cj  = bx % CHUNKS;             // chunk id (uniform)
    const int rt  = bx / CHUNKS;             // 128-row tile id, 0..127

    // ---- densify this chunk's weights into wd[64][16] (verified v2/v3) ----
    if (cj < 4) {                            // group 1: 4 blocks of 16->4
        const int wbase = cj * 256;
        #pragma unroll
        for (int i = 0; i < 8; ++i) {
            const int e = tid + i * 128, k = e >> 4, c = e & 15, b = k >> 4;
            wd[e] = ((c >> 2) == b)
                  ? w[wbase + b * 64 + ((k & 15) << 2) + (c & 3)] : 0.0f;
        }
    } else if (cj < 20) {                    // group 2: 2 blocks of 32->8
        const int wbase = 1024 + (cj - 4) * 512;
        #pragma unroll
        for (int i = 0; i < 8; ++i) {
            const int e = tid + i * 128, k = e >> 4, c = e & 15, b = k >> 5;
            wd[e] = ((c >> 3) == b)
                  ? w[wbase + b * 256 + ((k & 31) << 3) + (c & 7)] : 0.0f;
        }
    } else {                                 // group 3: dense 64->16 block
        const int wbase = 9216 + (cj - 20) * 1024;
        #pragma unroll
        for (int i = 0; i < 8; ++i) {
            const int e = tid + i * 128;
            wd[e] = w[wbase + e];
        }
    }
    __syncthreads();                         // only barrier: wd visibility

    const int wv   = tid >> 6;               // wave id 0/1
    const int lane = tid & 63;
    float* __restrict__ xsw = xs[wv];
    const int row0 = rt * 128 + wv * 64;     // wave's 64-row tile

    // ---- stage wave-private x tile (v2 pattern: 4 rows x 256 B per instr) --
    const float* __restrict__ xsrc = x + (size_t)row0 * IN_DIM + cj * 64;
    #pragma unroll
    for (int i = 0; i < 16; ++i) {
        const int f = (i << 6) + lane;       // 1024 float4s per tile
        const int r = f >> 4, c = (f & 15) << 2;
        const float4 v = *reinterpret_cast<const float4*>(
            xsrc + (size_t)r * IN_DIM + c);
        *reinterpret_cast<float4*>(&xsw[r * XS_LDW + c]) = v;
    }
    // no barrier: tile is wave-private (same-wave ds dep -> waitcnt only)

    // ---- compute: lane = (rq, cq) -> rows rq*4..+3, cols cq*4..+3 ----
    const int rq = lane >> 2;                // 0..15
    const int cq = lane & 3;                 // 0..3
    const float4 bv = *reinterpret_cast<const float4*>(
        bias + cj * 16 + (cq << 2));
    float4 acc[4] = {bv, bv, bv, bv};        // acc[i]: row rq*4+i

    const int xb = (rq << 2) * XS_LDW;       // row rq*4
    const int wb = cq << 2;
    #pragma unroll
    for (int k4 = 0; k4 < 16; ++k4) {
        const int kb = k4 << 2;
        float4 xv[4], wj[4];
        #pragma unroll
        for (int i = 0; i < 4; ++i)
            xv[i] = *reinterpret_cast<const float4*>(
                &xsw[xb + i * XS_LDW + kb]);
        #pragma unroll
        for (int j = 0; j < 4; ++j)
            wj[j] = *reinterpret_cast<const float4*>(
                &wd[(kb + j) * 16 + wb]);
        #pragma unroll
        for (int i = 0; i < 4; ++i) {
            acc[i].x += xv[i].x*wj[0].x + xv[i].y*wj[1].x + xv[i].z*wj[2].x + xv[i].w*wj[3].x;
            acc[i].y += xv[i].x*wj[0].y + xv[i].y*wj[1].y + xv[i].z*wj[2].y + xv[i].w*wj[3].y;
            acc[i].z += xv[i].x*wj[0].z + xv[i].y*wj[1].z + xv[i].z*wj[2].z + xv[i].w*wj[3].z;
            acc[i].w += xv[i].x*wj[0].w + xv[i].y*wj[1].w + xv[i].z*wj[2].w + xv[i].w*wj[3].w;
        }
    }

    // ---- store: per instr, 16 complete aligned 64-B runs (rq x cq) ----
    #pragma unroll
    for (int i = 0; i < 4; ++i)
        *reinterpret_cast<float4*>(
            out + (size_t)(row0 + (rq << 2) + i) * OUT_DIM
                + cj * 16 + (cq << 2)) = acc[i];
}

extern "C" void kernel_launch(void* const* d_in, const int* in_sizes, int n_in,
                              void* d_out, int out_size, void* d_ws, size_t ws_size,
                              hipStream_t stream) {
    const float* x    = (const float*)d_in[0];
    const float* w    = (const float*)d_in[1];
    const float* bias = (const float*)d_in[2];
    float* out        = (float*)d_out;

    // 36 chunks x (16384/128 = 128) row tiles
    fused_block_mm<<<dim3(CHUNKS * 128), 128, 0, stream>>>(x, w, bias, out);
}